// Round 21
// baseline (200.624 us; speedup 1.0000x reference)
//
#include <hip/hip_runtime.h>
#include <hip/hip_bf16.h>

// Problem constants (fixed by setup_inputs)
#define NB 16     // batch
#define CC 64     // channels
#define TT 64
#define VV 25
#define LL 1600   // T*V
#define HH 4
#define DD 64
#define NH 64     // N*H

// Dtype contract: d_in fp32, d_out fp32, tolerance bf16-grade.
// r13: attn K/V swizzle. r15: split=1 + prep fold. r16: conv9 A staging.
// r18: vf-hoist. r20: conv9 W-frag 1-step register prefetch -> 199.8us.
// Round-36 (this round): deepen conv9 W prefetch to 2 steps (L2 latency
// ~200+cy > ~100-150cy of per-step work; 1-step cover insufficient).
// Two buffer sets bbA/bbB; consume bbA, shift bbB->bbA, load t+2 into
// bbB; ALL loads unconditional with wraparound (zero undef, r17 lesson).

typedef __hip_bfloat16 bf16;
typedef __attribute__((ext_vector_type(8))) short short8;
typedef __attribute__((ext_vector_type(4))) float f32x4;
typedef __attribute__((ext_vector_type(4))) int int4v;
typedef __attribute__((ext_vector_type(4))) unsigned short us4;

__device__ __forceinline__ float b2f(bf16 v) { return __bfloat162float(v); }
__device__ __forceinline__ unsigned short f2bf_bits(float f) {
  bf16 h = __float2bfloat16(f);
  return *(unsigned short*)&h;
}
// pack two f32 -> bf16x2 by truncation: one v_perm_b32 (validated round 14)
__device__ __forceinline__ unsigned pkbf_trunc(float lo, float hi) {
  return __builtin_amdgcn_perm(__float_as_uint(hi), __float_as_uint(lo), 0x07060302u);
}
// xor-1 lane exchange via DPP quad_perm [1,0,3,2] (0xB1): VALU, not LDS.
__device__ __forceinline__ float dppx1(float x) {
  return __int_as_float(
      __builtin_amdgcn_mov_dpp(__float_as_int(x), 0xB1, 0xF, 0xF, true));
}
__device__ __forceinline__ int dppx1i(int x) {
  return __builtin_amdgcn_mov_dpp(x, 0xB1, 0xF, 0xF, true);
}
// gfx950 dual-register lane swaps (CDNA4): both operands read+written.
__device__ __forceinline__ void pl32swap(int &a, int &b) {
  asm("v_permlane32_swap_b32 %0, %1" : "+v"(a), "+v"(b));
}
__device__ __forceinline__ void pl16swap(int &a, int &b) {
  asm("v_permlane16_swap_b32 %0, %1" : "+v"(a), "+v"(b));
}

// ---------------------------------------------------------------------------
// K0: WqT-only weight prep (gates k_qkv). grid 192 x 256.
// ---------------------------------------------------------------------------
__global__ void k_prep_wq(const float* __restrict__ Wq, bf16* __restrict__ WqT) {
  int i = blockIdx.x * 256 + threadIdx.x;  // < 49152
  int jj = i & 7, lane = (i >> 3) & 63, g = i >> 9;  // g 0..95
  int nt = g % 48, half = g / 48;
  int ch = half * 32 + (lane >> 4) * 8 + jj;
  int j = nt * 16 + (lane & 15);
  WqT[i] = __float2bfloat16(Wq[ch * 768 + j]);
}

// ---------------------------------------------------------------------------
// K1: qkv projection as MFMA GEMM. 4 waves/block (grid 400 x 256);
// each wave = one 16-row l-tile, wave-private xa/tr slices, no barriers.
// ---------------------------------------------------------------------------
__global__ __launch_bounds__(256)
void k_qkv(const float* __restrict__ x, const bf16* __restrict__ WqT,
           const float* __restrict__ bq,
           bf16* __restrict__ q, bf16* __restrict__ k, bf16* __restrict__ vt) {
  __shared__ short xa_all[4][16 * 72];  // per-wave A-tile [16 l][64 c] (+pad)
  __shared__ short tr_all[4][16 * 66];  // per-wave transpose buffer
  int tid = threadIdx.x;
  int wv = tid >> 6, lane = tid & 63;
  int quad = lane >> 4, c = lane & 15;
  int g4 = blockIdx.x * 4 + wv;   // 0..1599: this wave's l-tile index
  int n = g4 / 100;
  int l0 = (g4 % 100) * 16;
  short* xa = xa_all[wv];
  short* tr = tr_all[wv];
  bool ev = (c & 1) == 0;

  {
    int l = c;
    const float* xb = x + (size_t)n * 102400 + (size_t)(quad * 16) * 1600 + l0 + l;
    unsigned short vb[16];
#pragma unroll
    for (int i = 0; i < 16; i++) vb[i] = f2bf_bits(xb[(size_t)i * 1600]);
    unsigned wrds[8];
#pragma unroll
    for (int i = 0; i < 8; i++)
      wrds[i] = ((unsigned)vb[2 * i + 1] << 16) | vb[2 * i];
    *(short8*)(xa + l * 72 + quad * 16) = *(short8*)&wrds[0];
    *(short8*)(xa + l * 72 + quad * 16 + 8) = *(short8*)&wrds[4];
  }
  asm volatile("" ::: "memory");
  short8 af0 = *(const short8*)(xa + c * 72 + quad * 8);
  short8 af1 = *(const short8*)(xa + c * 72 + 32 + quad * 8);

  const short* wq0 = (const short*)WqT;
  const float QSCALE = 0.125f * 1.44269504f;

  short8 bc[8], bn[8];
#pragma unroll
  for (int t = 0; t < 4; t++) {
    bc[2 * t]     = *(const short8*)(wq0 + ((size_t)t * 64 + lane) * 8);
    bc[2 * t + 1] = *(const short8*)(wq0 + ((size_t)(48 + t) * 64 + lane) * 8);
  }

#pragma unroll
  for (int g = 0; g < 12; g++) {
    int s = g >> 2, h = g & 3;
    // --- 4 output tiles of this group (uses prefetched bc) ---
    f32x4 z[4];
#pragma unroll
    for (int t = 0; t < 4; t++) {
      int nt = g * 4 + t;
      float bv = bq[nt * 16 + c];
      f32x4 zz = {bv, bv, bv, bv};
      zz = __builtin_amdgcn_mfma_f32_16x16x32_bf16(af0, bc[2 * t], zz, 0, 0, 0);
      zz = __builtin_amdgcn_mfma_f32_16x16x32_bf16(af1, bc[2 * t + 1], zz, 0, 0, 0);
      z[t] = zz;
    }
    // --- prefetch group g+1 B-frags BEFORE the clobber section ---
    if (g < 11) {
#pragma unroll
      for (int t = 0; t < 4; t++) {
        int nt = (g + 1) * 4 + t;
        bn[2 * t]     = *(const short8*)(wq0 + ((size_t)nt * 64 + lane) * 8);
        bn[2 * t + 1] = *(const short8*)(wq0 + ((size_t)(48 + nt) * 64 + lane) * 8);
      }
    }
    if (s < 2) {
      // q/k: tile-transpose via tr, coalesced 16B row stores
      asm volatile("" ::: "memory");
#pragma unroll
      for (int t = 0; t < 4; t++) {
        if (s == 0) {
#pragma unroll
          for (int r = 0; r < 4; r++) z[t][r] *= QSCALE;
        }
        int us_[4];
#pragma unroll
        for (int r = 0; r < 4; r++) us_[r] = f2bf_bits(z[t][r]);
        int xv0 = dppx1i(us_[0]);
        int xv1 = dppx1i(us_[1]);
        int xv2 = dppx1i(us_[2]);
        int xv3 = dppx1i(us_[3]);
        if (ev) {
          *(int*)(tr + (quad * 4 + 0) * 66 + t * 16 + c) = (xv0 << 16) | us_[0];
          *(int*)(tr + (quad * 4 + 1) * 66 + t * 16 + c) = (xv1 << 16) | us_[1];
        } else {
          *(int*)(tr + (quad * 4 + 2) * 66 + t * 16 + (c - 1)) = (us_[2] << 16) | xv2;
          *(int*)(tr + (quad * 4 + 3) * 66 + t * 16 + (c - 1)) = (us_[3] << 16) | xv3;
        }
      }
      asm volatile("" ::: "memory");
      int row = lane >> 2, seg = lane & 3;
      short8 o0 = *(const short8*)(tr + row * 66 + seg * 16);
      short8 o1 = *(const short8*)(tr + row * 66 + seg * 16 + 8);
      short* dstp = (short*)(s == 0 ? q : k);
      short* dst = dstp + ((size_t)(n * 4 + h) * 1600 + l0 + row) * 64 + seg * 16;
      *(short8*)(dst) = o0;
      *(short8*)(dst + 8) = o1;
      asm volatile("" ::: "memory");  // tr reused next group
    } else {
      // v: direct stores to vt[nh][d][l]
#pragma unroll
      for (int t = 0; t < 4; t++) {
        us4 pk;
#pragma unroll
        for (int r = 0; r < 4; r++) pk[r] = f2bf_bits(z[t][r]);
        *(us4*)((short*)vt + ((size_t)((n * 4 + h) * 64 + t * 16 + c)) * 1600 +
                l0 + quad * 4) = pk;
      }
    }
#pragma unroll
    for (int i = 0; i < 8; i++) bc[i] = bn[i];
  }
}

// ---------------------------------------------------------------------------
// K2: MFMA flash attention (round-18 structure: single-buffer, vf-hoist,
// split=1, Wt/WfT prep grid tail). 4 waves x 1 q-tile per 256-thread
// block; K/V LDS XOR-swizzled; 2 barriers/kt. grid 1600+576, block 256.
// ---------------------------------------------------------------------------
__global__ __launch_bounds__(256, 2)
void k_attn(const bf16* __restrict__ q, const bf16* __restrict__ k,
            const bf16* __restrict__ vt, bf16* __restrict__ po,
            const float* __restrict__ Wo, const float* __restrict__ Wf,
            bf16* __restrict__ Wt, bf16* __restrict__ WfT) {
  __shared__ short kbuf[64 * 64];       // K tile [kv][d], swizzled segs
  __shared__ short vbuf[64 * 64];       // V tile [d][kv], swizzled segs
  __shared__ short pl_all[4][16 * 66];  // epilogue transpose only
  int tid = threadIdx.x;
  int bid = blockIdx.x;
  // --- grid-tail: Wt/WfT weight prep (consumed by k_conv9, launched later).
  if (bid >= 1600) {
    int i = (bid - 1600) * 256 + tid;   // 0..147455
    {
      int j = i & 7, lane = (i >> 3) & 63, cot = (i >> 9) & 3;
      int kc = (i >> 11) & 7, r = i >> 14;
      int co = cot * 16 + (lane & 15);
      int ci = kc * 32 + (lane >> 4) * 8 + j;
      Wt[i] = __float2bfloat16(Wo[(co * 256 + ci) * 9 + r]);
    }
    if (i < 4096) {
      int j = i & 7, lane = (i >> 3) & 63, cot = (i >> 9) & 3, kc = (i >> 11) & 1;
      int co = cot * 16 + (lane & 15);
      int ci = kc * 32 + (lane >> 4) * 8 + j;
      WfT[i] = __float2bfloat16(Wf[co * 64 + ci]);
    }
    return;
  }
  int wv = tid >> 6, lane = tid & 63;
  int quad = lane >> 4, c = lane & 15;
  int xcd = bid & 7;
  int slot = bid >> 3;
  int qt = slot % 25, grp = slot / 25;
  int nh = grp * 8 + xcd;          // nh%8 == bid%8 -> per-XCD K/V stream
  int l0 = qt * 64 + wv * 16;      // each wave owns ONE 16-row q-tile
  short* pl = pl_all[wv];

  const short* qbase = (const short*)q + ((size_t)nh * 1600 + l0 + c) * 64 + quad * 8;
  short8 qf0 = *(const short8*)(qbase);
  short8 qf1 = *(const short8*)(qbase + 32);

  short ob = (c == 0) ? (short)0x3F80 : (short)0;  // bf16 1.0 in col 0
  short8 onesf = {ob, ob, ob, ob, ob, ob, ob, ob};

  f32x4 acc[5] = {};  // 4 d-tiles + l-tile (ones-trick)

  const short* kg = (const short*)k + (size_t)nh * 102400;
  const short* vg = (const short*)vt + (size_t)nh * 102400;
  bool ev = (c & 1) == 0;

  // swizzled LDS offsets (precomputed per lane)
  int wrow = tid >> 3;                       // staging row for i=0 (row+32 for i=1)
  int wseg = (tid & 7) ^ (wrow & 7);         // write seg ((row+32)&7 == row&7)
  int cx = c & 7;
  int rseg0 = quad ^ cx;                     // read seg for kf0/vf0
  int rseg1 = (quad + 4) ^ cx;               // read seg for kf1/vf1

  // prefetch K and V tiles for kt=0 (256 threads x 2 short8 each)
  short8 sk[2], sv[2];
  {
    const short8* gk = (const short8*)(kg);
#pragma unroll
    for (int i = 0; i < 2; i++) sk[i] = gk[tid + i * 256];
#pragma unroll
    for (int i = 0; i < 2; i++) {
      int ch = tid + i * 256;
      sv[i] = *(const short8*)(vg + (size_t)(ch >> 3) * 1600 + (ch & 7) * 8);
    }
  }

  for (int kt = 0; kt < 25; kt++) {
    __syncthreads();
#pragma unroll
    for (int i = 0; i < 2; i++) {
      int row = wrow + i * 32;
      *(short8*)(kbuf + row * 64 + wseg * 8) = sk[i];
      *(short8*)(vbuf + row * 64 + wseg * 8) = sv[i];
    }
    __syncthreads();
    // prefetch K+V for NEXT kt (pinned by next iteration's barrier;
    // conditional is safe: sk/sv unused after the final iteration).
    if (kt + 1 < 25) {
      const short8* gk = (const short8*)(kg + (kt + 1) * 4096);
#pragma unroll
      for (int i = 0; i < 2; i++) sk[i] = gk[tid + i * 256];
#pragma unroll
      for (int i = 0; i < 2; i++) {
        int ch = tid + i * 256;
        sv[i] = *(const short8*)(vg + (size_t)(ch >> 3) * 1600 + (kt + 1) * 64 + (ch & 7) * 8);
      }
    }
    // QK^T swapped: s[ct] = D[m=kv(ct tile)][n=q], bias -8.
    f32x4 s[4];
#pragma unroll
    for (int ct = 0; ct < 4; ct++) {
      const short* kr = kbuf + (ct * 16 + c) * 64;
      short8 kf0 = *(const short8*)(kr + rseg0 * 8);
      short8 kf1 = *(const short8*)(kr + rseg1 * 8);
      f32x4 z0 = {-8.f, -8.f, -8.f, -8.f};
      z0 = __builtin_amdgcn_mfma_f32_16x16x32_bf16(kf0, qf0, z0, 0, 0, 0);
      z0 = __builtin_amdgcn_mfma_f32_16x16x32_bf16(kf1, qf1, z0, 0, 0, 0);
      s[ct] = z0;
    }
    // V fragments issued BEFORE the exp chain (latency hides under exp).
    short8 vf[4][2];
#pragma unroll
    for (int ct = 0; ct < 4; ct++) {
      const short* vr = vbuf + (ct * 16 + c) * 64;
      vf[ct][0] = *(const short8*)(vr + rseg0 * 8);
      vf[ct][1] = *(const short8*)(vr + rseg1 * 8);
    }
#pragma unroll
    for (int ct = 0; ct < 4; ct++)
#pragma unroll
      for (int r = 0; r < 4; r++) s[ct][r] = exp2f(s[ct][r]);
    // In-register P -> A-frag redistribution (T12-style, zero LDS).
    {
      int wA[4], wB[4];
#pragma unroll
      for (int ct = 0; ct < 4; ct++) {
        wA[ct] = (int)pkbf_trunc(s[ct][0], s[ct][1]);
        wB[ct] = (int)pkbf_trunc(s[ct][2], s[ct][3]);
      }
      // frag0 (kv 0..31 from ct0,ct1): words j0..j3 at quad q = kv q*8+2j.
      pl32swap(wA[0], wA[1]); pl16swap(wA[0], wA[1]);  // wA0=j0, wA1=j2
      pl32swap(wB[0], wB[1]); pl16swap(wB[0], wB[1]);  // wB0=j1, wB1=j3
      int4v f0 = {wA[0], wB[0], wA[1], wB[1]};
      // frag1 (kv 32..63 from ct2,ct3)
      pl32swap(wA[2], wA[3]); pl16swap(wA[2], wA[3]);
      pl32swap(wB[2], wB[3]); pl16swap(wB[2], wB[3]);
      int4v f1 = {wA[2], wB[2], wA[3], wB[3]};
      short8 pf0 = *(short8*)&f0;
      short8 pf1 = *(short8*)&f1;
#pragma unroll
      for (int ct = 0; ct < 4; ct++) {
        acc[ct] = __builtin_amdgcn_mfma_f32_16x16x32_bf16(pf0, vf[ct][0], acc[ct], 0, 0, 0);
        acc[ct] = __builtin_amdgcn_mfma_f32_16x16x32_bf16(pf1, vf[ct][1], acc[ct], 0, 0, 0);
      }
      acc[4] = __builtin_amdgcn_mfma_f32_16x16x32_bf16(pf0, onesf, acc[4], 0, 0, 0);
      acc[4] = __builtin_amdgcn_mfma_f32_16x16x32_bf16(pf1, onesf, acc[4], 0, 0, 0);
    }
  }
  int n = nh >> 2, h = nh & 3;
  {
    float linv[4];
#pragma unroll
    for (int r = 0; r < 4; r++)
      linv[r] = 1.0f / __shfl(acc[4][r], lane & 48);
    asm volatile("" ::: "memory");
#pragma unroll
    for (int t = 0; t < 4; t++) {
      int us_[4];
#pragma unroll
      for (int r = 0; r < 4; r++) us_[r] = f2bf_bits(acc[t][r] * linv[r]);
      int xv0 = dppx1i(us_[0]);
      int xv1 = dppx1i(us_[1]);
      int xv2 = dppx1i(us_[2]);
      int xv3 = dppx1i(us_[3]);
      if (ev) {
        *(int*)(pl + (quad * 4 + 0) * 66 + t * 16 + c) = (xv0 << 16) | us_[0];
        *(int*)(pl + (quad * 4 + 1) * 66 + t * 16 + c) = (xv1 << 16) | us_[1];
      } else {
        *(int*)(pl + (quad * 4 + 2) * 66 + t * 16 + (c - 1)) = (us_[2] << 16) | xv2;
        *(int*)(pl + (quad * 4 + 3) * 66 + t * 16 + (c - 1)) = (us_[3] << 16) | xv3;
      }
    }
    asm volatile("" ::: "memory");
    int row = lane >> 2, seg = lane & 3;
    short8 o0 = *(const short8*)(pl + row * 66 + seg * 16);
    short8 o1 = *(const short8*)(pl + row * 66 + seg * 16 + 8);
    short* dst = (short*)po +
                 ((size_t)n * 1600 + l0 + row) * 256 + h * 64 + seg * 16;
    *(short8*)(dst) = o0;
    *(short8*)(dst + 8) = o1;
    asm volatile("" ::: "memory");
  }
}

// ---------------------------------------------------------------------------
// K3: fused (1,9)conv+BN1+res+relu -> 1x1conv+BN2+res+relu -> d_out.
// A-tile staged in LDS (r16); round-36: W-frags in a 2-DEEP register
// pipeline (consume bbA, shift bbB->bbA, load step t+2 into bbB; all
// loads unconditional wraparound). grid (25,16) x 256.
// ---------------------------------------------------------------------------
__global__ __launch_bounds__(256)
void k_conv9(const bf16* __restrict__ ot, const bf16* __restrict__ Wt,
             const float* __restrict__ bo, const float* __restrict__ g1,
             const float* __restrict__ be1, const float* __restrict__ mu1,
             const float* __restrict__ va1, const float* __restrict__ x,
             const bf16* __restrict__ WfT, const float* __restrict__ bff,
             const float* __restrict__ g2, const float* __restrict__ be2,
             const float* __restrict__ mu2, const float* __restrict__ va2,
             float* __restrict__ out) {
  __shared__ short abuf[72 * 256];  // ot rows l0b-4..l0b+67, swizzled segs
  __shared__ short tl[4][16 * 66];
  int tid = threadIdx.x;
  int wv = tid >> 6;
  int lane = tid & 63;
  int quad = lane >> 4, c = lane & 15;
  int n = blockIdx.y;
  int l0b = blockIdx.x * 64;
  int l0 = l0b + wv * 16;
  int la = l0 + c;
  int va = la % 25;
  const short* obase = (const short*)ot + (size_t)n * 409600;
  const short* wbase = (const short*)Wt;

  // --- stage A rows [l0b-4, l0b+68) into LDS (coalesced, swizzled) ---
#pragma unroll
  for (int it = 0; it < 9; it++) {
    int ch = tid + it * 256;
    int row = ch >> 5, seg = ch & 31;
    int gl = l0b - 4 + row;
    gl = max(0, min(1599, gl));  // clamp; clamped rows only feed masked lanes
    short8 v = *(const short8*)(obase + (size_t)gl * 256 + seg * 8);
    *(short8*)(abuf + row * 256 + (seg ^ (row & 7)) * 8) = v;
  }
  __syncthreads();

  f32x4 acc[4] = {};
  // W-frag 2-deep register pipeline: preload steps 0 and 1.
  short8 bbA[4], bbB[4];
  {
    const short* p0 = wbase + lane * 8;          // step 0 (r0,kc0)
    const short* p1 = wbase + 2048 + lane * 8;   // step 1 (r0,kc1)
#pragma unroll
    for (int j = 0; j < 4; j++) {
      bbA[j] = *(const short8*)(p0 + j * 512);
      bbB[j] = *(const short8*)(p1 + j * 512);
    }
  }
  for (int r = 0; r < 9; r++) {
    int sh = r - 4;
    bool valid = (unsigned)(va + sh) < 25u;
    int rl = wv * 16 + c + r;        // row in abuf (always in [0,71])
    int rx = rl & 7;
    const short* arow = abuf + rl * 256;
    short8 z8 = {0, 0, 0, 0, 0, 0, 0, 0};
#pragma unroll
    for (int kc = 0; kc < 8; kc++) {
      short8 b0 = bbA[0], b1 = bbA[1], b2 = bbA[2], b3 = bbA[3];
#pragma unroll
      for (int j = 0; j < 4; j++) bbA[j] = bbB[j];
      // issue load for step t+2 (wraparound keeps every load valid).
      int t = r * 8 + kc;
      int tn = t + 2;
      if (tn >= 72) tn -= 72;
      const short* wkn = wbase + (size_t)(tn >> 3) * 16384 + (tn & 7) * 2048 + lane * 8;
#pragma unroll
      for (int j = 0; j < 4; j++) bbB[j] = *(const short8*)(wkn + j * 512);
      asm volatile("" ::: "memory");  // pin prefetch issue point
      int seg = (quad + kc * 4) ^ rx;
      short8 af = *(const short8*)(arow + seg * 8);
      af = valid ? af : z8;
      acc[0] = __builtin_amdgcn_mfma_f32_16x16x32_bf16(af, b0, acc[0], 0, 0, 0);
      acc[1] = __builtin_amdgcn_mfma_f32_16x16x32_bf16(af, b1, acc[1], 0, 0, 0);
      acc[2] = __builtin_amdgcn_mfma_f32_16x16x32_bf16(af, b2, acc[2], 0, 0, 0);
      acc[3] = __builtin_amdgcn_mfma_f32_16x16x32_bf16(af, b3, acc[3], 0, 0, 0);
    }
  }
  // --- epilogue 1: BN1 + bias + residual x + relu -> outv (regs only) ---
  short* tlw = &tl[wv][0];
  float outv[4][4];
#pragma unroll
  for (int cot = 0; cot < 4; cot++) {
    int co = cot * 16 + c;
    float inv = g1[co] * rsqrtf(va1[co] + 1e-5f);
    float add = be1[co] - mu1[co] * inv + bo[co] * inv;
    f32x4 xr = *(const f32x4*)(x + (size_t)(n * 64 + co) * 1600 + l0 + quad * 4);
#pragma unroll
    for (int rr = 0; rr < 4; rr++)
      outv[cot][rr] = fmaxf(acc[cot][rr] * inv + add + xr[rr], 0.f);
  }
  // --- y^T tile via wave-private LDS [16 l][66 ci] (DPP pairing) ---
  asm volatile("" ::: "memory");
  bool ev = (c & 1) == 0;
#pragma unroll
  for (int cot = 0; cot < 4; cot++) {
    int us_[4];
#pragma unroll
    for (int rr = 0; rr < 4; rr++) us_[rr] = f2bf_bits(outv[cot][rr]);
    int xv0 = dppx1i(us_[0]);
    int xv1 = dppx1i(us_[1]);
    int xv2 = dppx1i(us_[2]);
    int xv3 = dppx1i(us_[3]);
    if (ev) {
      *(int*)(tlw + (quad * 4 + 0) * 66 + cot * 16 + c) = (xv0 << 16) | us_[0];
      *(int*)(tlw + (quad * 4 + 1) * 66 + cot * 16 + c) = (xv1 << 16) | us_[1];
    } else {
      *(int*)(tlw + (quad * 4 + 2) * 66 + cot * 16 + (c - 1)) = (us_[2] << 16) | xv2;
      *(int*)(tlw + (quad * 4 + 3) * 66 + cot * 16 + (c - 1)) = (us_[3] << 16) | xv3;
    }
  }
  asm volatile("" ::: "memory");
  // --- fused ff: A-frags straight from tl (A[m=l][k=ci]) ---
  short8 afY0 = *(const short8*)(tlw + c * 66 + quad * 8);
  short8 afY1 = *(const short8*)(tlw + c * 66 + 32 + quad * 8);
  const short* wfb = (const short*)WfT + lane * 8;
  f32x4 acc2[4] = {};
#pragma unroll
  for (int kc = 0; kc < 2; kc++) {
    short8 afk = kc ? afY1 : afY0;
    const short* wk = wfb + kc * 2048;
    short8 b0 = *(const short8*)(wk);
    short8 b1 = *(const short8*)(wk + 512);
    short8 b2 = *(const short8*)(wk + 1024);
    short8 b3 = *(const short8*)(wk + 1536);
    acc2[0] = __builtin_amdgcn_mfma_f32_16x16x32_bf16(afk, b0, acc2[0], 0, 0, 0);
    acc2[1] = __builtin_amdgcn_mfma_f32_16x16x32_bf16(afk, b1, acc2[1], 0, 0, 0);
    acc2[2] = __builtin_amdgcn_mfma_f32_16x16x32_bf16(afk, b2, acc2[2], 0, 0, 0);
    acc2[3] = __builtin_amdgcn_mfma_f32_16x16x32_bf16(afk, b3, acc2[3], 0, 0, 0);
  }
  // --- epilogue 2: BN2 + bias + residual y(=outv) + relu -> d_out fp32 ---
#pragma unroll
  for (int cot = 0; cot < 4; cot++) {
    int co = cot * 16 + c;
    float inv = g2[co] * rsqrtf(va2[co] + 1e-5f);
    float add = be2[co] - mu2[co] * inv + bff[co] * inv;
    f32x4 ov;
#pragma unroll
    for (int rr = 0; rr < 4; rr++)
      ov[rr] = fmaxf(acc2[cot][rr] * inv + add + outv[cot][rr], 0.f);
    *(f32x4*)(out + (size_t)(n * 64 + co) * 1600 + l0 + quad * 4) = ov;
  }
}

extern "C" void kernel_launch(void* const* d_in, const int* in_sizes, int n_in,
                              void* d_out, int out_size, void* d_ws, size_t ws_size,
                              hipStream_t stream) {
  const float* x   = (const float*)d_in[0];
  const float* Wq  = (const float*)d_in[1];
  const float* bq  = (const float*)d_in[2];
  const float* Wo  = (const float*)d_in[3];
  const float* bo  = (const float*)d_in[4];
  const float* g1  = (const float*)d_in[5];
  const float* be1 = (const float*)d_in[6];
  const float* mu1 = (const float*)d_in[7];
  const float* va1 = (const float*)d_in[8];
  const float* Wf  = (const float*)d_in[9];
  const float* bff = (const float*)d_in[10];
  const float* g2  = (const float*)d_in[11];
  const float* be2 = (const float*)d_in[12];
  const float* mu2 = (const float*)d_in[13];
  const float* va2 = (const float*)d_in[14];

  const size_t QKV = (size_t)64 * 1600 * 64;  // 6,553,600 bf16 elems
  // split=1 layout: q,k,vt,po (4*QKV) + weights. ~52.8 MB.
  bf16* qw  = (bf16*)d_ws;
  bf16* kw  = qw + QKV;
  bf16* vtw = kw + QKV;
  bf16* pow_ = vtw + QKV;                      // po == ot for conv9
  bf16* Wt  = pow_ + QKV;
  bf16* WfT = Wt + 147456;
  bf16* WqT = WfT + 4096;

  k_prep_wq<<<192, 256, 0, stream>>>(Wq, WqT);
  k_qkv<<<400, 256, 0, stream>>>(x, WqT, bq, qw, kw, vtw);
  k_attn<<<1600 + 576, 256, 0, stream>>>(qw, kw, vtw, pow_, Wo, Wf, Wt, WfT);
  dim3 gc(25, 16);
  k_conv9<<<gc, 256, 0, stream>>>(pow_, Wt, bo, g1, be1, mu1, va1, x,
                                  WfT, bff, g2, be2, mu2, va2, (float*)d_out);
}

// Round 22
// 197.414 us; speedup vs baseline: 1.0163x; 1.0163x over previous
//
#include <hip/hip_runtime.h>
#include <hip/hip_bf16.h>

// Problem constants (fixed by setup_inputs)
#define NB 16     // batch
#define CC 64     // channels
#define TT 64
#define VV 25
#define LL 1600   // T*V
#define HH 4
#define DD 64
#define NH 64     // N*H

// FINAL (round-37 = round-20 revert, best measured 199.8us):
// r13: attn K/V swizzle. r15: split=1 + prep fold. r16: conv9 A staging.
// r18: vf-hoist. r20: conv9 W-frag 1-step register prefetch.
// r21's 2-step W pipeline was neutral-negative -> reverted to 1-step.

typedef __hip_bfloat16 bf16;
typedef __attribute__((ext_vector_type(8))) short short8;
typedef __attribute__((ext_vector_type(4))) float f32x4;
typedef __attribute__((ext_vector_type(4))) int int4v;
typedef __attribute__((ext_vector_type(4))) unsigned short us4;

__device__ __forceinline__ float b2f(bf16 v) { return __bfloat162float(v); }
__device__ __forceinline__ unsigned short f2bf_bits(float f) {
  bf16 h = __float2bfloat16(f);
  return *(unsigned short*)&h;
}
// pack two f32 -> bf16x2 by truncation: one v_perm_b32 (validated round 14)
__device__ __forceinline__ unsigned pkbf_trunc(float lo, float hi) {
  return __builtin_amdgcn_perm(__float_as_uint(hi), __float_as_uint(lo), 0x07060302u);
}
// xor-1 lane exchange via DPP quad_perm [1,0,3,2] (0xB1): VALU, not LDS.
__device__ __forceinline__ float dppx1(float x) {
  return __int_as_float(
      __builtin_amdgcn_mov_dpp(__float_as_int(x), 0xB1, 0xF, 0xF, true));
}
__device__ __forceinline__ int dppx1i(int x) {
  return __builtin_amdgcn_mov_dpp(x, 0xB1, 0xF, 0xF, true);
}
// gfx950 dual-register lane swaps (CDNA4): both operands read+written.
__device__ __forceinline__ void pl32swap(int &a, int &b) {
  asm("v_permlane32_swap_b32 %0, %1" : "+v"(a), "+v"(b));
}
__device__ __forceinline__ void pl16swap(int &a, int &b) {
  asm("v_permlane16_swap_b32 %0, %1" : "+v"(a), "+v"(b));
}

// ---------------------------------------------------------------------------
// K0: WqT-only weight prep (gates k_qkv). grid 192 x 256.
// ---------------------------------------------------------------------------
__global__ void k_prep_wq(const float* __restrict__ Wq, bf16* __restrict__ WqT) {
  int i = blockIdx.x * 256 + threadIdx.x;  // < 49152
  int jj = i & 7, lane = (i >> 3) & 63, g = i >> 9;  // g 0..95
  int nt = g % 48, half = g / 48;
  int ch = half * 32 + (lane >> 4) * 8 + jj;
  int j = nt * 16 + (lane & 15);
  WqT[i] = __float2bfloat16(Wq[ch * 768 + j]);
}

// ---------------------------------------------------------------------------
// K1: qkv projection as MFMA GEMM. 4 waves/block (grid 400 x 256);
// each wave = one 16-row l-tile, wave-private xa/tr slices, no barriers.
// ---------------------------------------------------------------------------
__global__ __launch_bounds__(256)
void k_qkv(const float* __restrict__ x, const bf16* __restrict__ WqT,
           const float* __restrict__ bq,
           bf16* __restrict__ q, bf16* __restrict__ k, bf16* __restrict__ vt) {
  __shared__ short xa_all[4][16 * 72];  // per-wave A-tile [16 l][64 c] (+pad)
  __shared__ short tr_all[4][16 * 66];  // per-wave transpose buffer
  int tid = threadIdx.x;
  int wv = tid >> 6, lane = tid & 63;
  int quad = lane >> 4, c = lane & 15;
  int g4 = blockIdx.x * 4 + wv;   // 0..1599: this wave's l-tile index
  int n = g4 / 100;
  int l0 = (g4 % 100) * 16;
  short* xa = xa_all[wv];
  short* tr = tr_all[wv];
  bool ev = (c & 1) == 0;

  {
    int l = c;
    const float* xb = x + (size_t)n * 102400 + (size_t)(quad * 16) * 1600 + l0 + l;
    unsigned short vb[16];
#pragma unroll
    for (int i = 0; i < 16; i++) vb[i] = f2bf_bits(xb[(size_t)i * 1600]);
    unsigned wrds[8];
#pragma unroll
    for (int i = 0; i < 8; i++)
      wrds[i] = ((unsigned)vb[2 * i + 1] << 16) | vb[2 * i];
    *(short8*)(xa + l * 72 + quad * 16) = *(short8*)&wrds[0];
    *(short8*)(xa + l * 72 + quad * 16 + 8) = *(short8*)&wrds[4];
  }
  asm volatile("" ::: "memory");
  short8 af0 = *(const short8*)(xa + c * 72 + quad * 8);
  short8 af1 = *(const short8*)(xa + c * 72 + 32 + quad * 8);

  const short* wq0 = (const short*)WqT;
  const float QSCALE = 0.125f * 1.44269504f;

  short8 bc[8], bn[8];
#pragma unroll
  for (int t = 0; t < 4; t++) {
    bc[2 * t]     = *(const short8*)(wq0 + ((size_t)t * 64 + lane) * 8);
    bc[2 * t + 1] = *(const short8*)(wq0 + ((size_t)(48 + t) * 64 + lane) * 8);
  }

#pragma unroll
  for (int g = 0; g < 12; g++) {
    int s = g >> 2, h = g & 3;
    // --- 4 output tiles of this group (uses prefetched bc) ---
    f32x4 z[4];
#pragma unroll
    for (int t = 0; t < 4; t++) {
      int nt = g * 4 + t;
      float bv = bq[nt * 16 + c];
      f32x4 zz = {bv, bv, bv, bv};
      zz = __builtin_amdgcn_mfma_f32_16x16x32_bf16(af0, bc[2 * t], zz, 0, 0, 0);
      zz = __builtin_amdgcn_mfma_f32_16x16x32_bf16(af1, bc[2 * t + 1], zz, 0, 0, 0);
      z[t] = zz;
    }
    // --- prefetch group g+1 B-frags BEFORE the clobber section ---
    if (g < 11) {
#pragma unroll
      for (int t = 0; t < 4; t++) {
        int nt = (g + 1) * 4 + t;
        bn[2 * t]     = *(const short8*)(wq0 + ((size_t)nt * 64 + lane) * 8);
        bn[2 * t + 1] = *(const short8*)(wq0 + ((size_t)(48 + nt) * 64 + lane) * 8);
      }
    }
    if (s < 2) {
      // q/k: tile-transpose via tr, coalesced 16B row stores
      asm volatile("" ::: "memory");
#pragma unroll
      for (int t = 0; t < 4; t++) {
        if (s == 0) {
#pragma unroll
          for (int r = 0; r < 4; r++) z[t][r] *= QSCALE;
        }
        int us_[4];
#pragma unroll
        for (int r = 0; r < 4; r++) us_[r] = f2bf_bits(z[t][r]);
        int xv0 = dppx1i(us_[0]);
        int xv1 = dppx1i(us_[1]);
        int xv2 = dppx1i(us_[2]);
        int xv3 = dppx1i(us_[3]);
        if (ev) {
          *(int*)(tr + (quad * 4 + 0) * 66 + t * 16 + c) = (xv0 << 16) | us_[0];
          *(int*)(tr + (quad * 4 + 1) * 66 + t * 16 + c) = (xv1 << 16) | us_[1];
        } else {
          *(int*)(tr + (quad * 4 + 2) * 66 + t * 16 + (c - 1)) = (us_[2] << 16) | xv2;
          *(int*)(tr + (quad * 4 + 3) * 66 + t * 16 + (c - 1)) = (us_[3] << 16) | xv3;
        }
      }
      asm volatile("" ::: "memory");
      int row = lane >> 2, seg = lane & 3;
      short8 o0 = *(const short8*)(tr + row * 66 + seg * 16);
      short8 o1 = *(const short8*)(tr + row * 66 + seg * 16 + 8);
      short* dstp = (short*)(s == 0 ? q : k);
      short* dst = dstp + ((size_t)(n * 4 + h) * 1600 + l0 + row) * 64 + seg * 16;
      *(short8*)(dst) = o0;
      *(short8*)(dst + 8) = o1;
      asm volatile("" ::: "memory");  // tr reused next group
    } else {
      // v: direct stores to vt[nh][d][l]
#pragma unroll
      for (int t = 0; t < 4; t++) {
        us4 pk;
#pragma unroll
        for (int r = 0; r < 4; r++) pk[r] = f2bf_bits(z[t][r]);
        *(us4*)((short*)vt + ((size_t)((n * 4 + h) * 64 + t * 16 + c)) * 1600 +
                l0 + quad * 4) = pk;
      }
    }
#pragma unroll
    for (int i = 0; i < 8; i++) bc[i] = bn[i];
  }
}

// ---------------------------------------------------------------------------
// K2: MFMA flash attention (single-buffer, vf-hoist, split=1, Wt/WfT prep
// grid tail). 4 waves x 1 q-tile per 256-thread block; K/V LDS
// XOR-swizzled; 2 barriers/kt. grid 1600+576, block 256.
// ---------------------------------------------------------------------------
__global__ __launch_bounds__(256, 2)
void k_attn(const bf16* __restrict__ q, const bf16* __restrict__ k,
            const bf16* __restrict__ vt, bf16* __restrict__ po,
            const float* __restrict__ Wo, const float* __restrict__ Wf,
            bf16* __restrict__ Wt, bf16* __restrict__ WfT) {
  __shared__ short kbuf[64 * 64];       // K tile [kv][d], swizzled segs
  __shared__ short vbuf[64 * 64];       // V tile [d][kv], swizzled segs
  __shared__ short pl_all[4][16 * 66];  // epilogue transpose only
  int tid = threadIdx.x;
  int bid = blockIdx.x;
  // --- grid-tail: Wt/WfT weight prep (consumed by k_conv9, launched later).
  if (bid >= 1600) {
    int i = (bid - 1600) * 256 + tid;   // 0..147455
    {
      int j = i & 7, lane = (i >> 3) & 63, cot = (i >> 9) & 3;
      int kc = (i >> 11) & 7, r = i >> 14;
      int co = cot * 16 + (lane & 15);
      int ci = kc * 32 + (lane >> 4) * 8 + j;
      Wt[i] = __float2bfloat16(Wo[(co * 256 + ci) * 9 + r]);
    }
    if (i < 4096) {
      int j = i & 7, lane = (i >> 3) & 63, cot = (i >> 9) & 3, kc = (i >> 11) & 1;
      int co = cot * 16 + (lane & 15);
      int ci = kc * 32 + (lane >> 4) * 8 + j;
      WfT[i] = __float2bfloat16(Wf[co * 64 + ci]);
    }
    return;
  }
  int wv = tid >> 6, lane = tid & 63;
  int quad = lane >> 4, c = lane & 15;
  int xcd = bid & 7;
  int slot = bid >> 3;
  int qt = slot % 25, grp = slot / 25;
  int nh = grp * 8 + xcd;          // nh%8 == bid%8 -> per-XCD K/V stream
  int l0 = qt * 64 + wv * 16;      // each wave owns ONE 16-row q-tile
  short* pl = pl_all[wv];

  const short* qbase = (const short*)q + ((size_t)nh * 1600 + l0 + c) * 64 + quad * 8;
  short8 qf0 = *(const short8*)(qbase);
  short8 qf1 = *(const short8*)(qbase + 32);

  short ob = (c == 0) ? (short)0x3F80 : (short)0;  // bf16 1.0 in col 0
  short8 onesf = {ob, ob, ob, ob, ob, ob, ob, ob};

  f32x4 acc[5] = {};  // 4 d-tiles + l-tile (ones-trick)

  const short* kg = (const short*)k + (size_t)nh * 102400;
  const short* vg = (const short*)vt + (size_t)nh * 102400;
  bool ev = (c & 1) == 0;

  // swizzled LDS offsets (precomputed per lane)
  int wrow = tid >> 3;                       // staging row for i=0 (row+32 for i=1)
  int wseg = (tid & 7) ^ (wrow & 7);         // write seg ((row+32)&7 == row&7)
  int cx = c & 7;
  int rseg0 = quad ^ cx;                     // read seg for kf0/vf0
  int rseg1 = (quad + 4) ^ cx;               // read seg for kf1/vf1

  // prefetch K and V tiles for kt=0 (256 threads x 2 short8 each)
  short8 sk[2], sv[2];
  {
    const short8* gk = (const short8*)(kg);
#pragma unroll
    for (int i = 0; i < 2; i++) sk[i] = gk[tid + i * 256];
#pragma unroll
    for (int i = 0; i < 2; i++) {
      int ch = tid + i * 256;
      sv[i] = *(const short8*)(vg + (size_t)(ch >> 3) * 1600 + (ch & 7) * 8);
    }
  }

  for (int kt = 0; kt < 25; kt++) {
    __syncthreads();
#pragma unroll
    for (int i = 0; i < 2; i++) {
      int row = wrow + i * 32;
      *(short8*)(kbuf + row * 64 + wseg * 8) = sk[i];
      *(short8*)(vbuf + row * 64 + wseg * 8) = sv[i];
    }
    __syncthreads();
    // prefetch K+V for NEXT kt (pinned by next iteration's barrier;
    // conditional is safe: sk/sv unused after the final iteration).
    if (kt + 1 < 25) {
      const short8* gk = (const short8*)(kg + (kt + 1) * 4096);
#pragma unroll
      for (int i = 0; i < 2; i++) sk[i] = gk[tid + i * 256];
#pragma unroll
      for (int i = 0; i < 2; i++) {
        int ch = tid + i * 256;
        sv[i] = *(const short8*)(vg + (size_t)(ch >> 3) * 1600 + (kt + 1) * 64 + (ch & 7) * 8);
      }
    }
    // QK^T swapped: s[ct] = D[m=kv(ct tile)][n=q], bias -8.
    f32x4 s[4];
#pragma unroll
    for (int ct = 0; ct < 4; ct++) {
      const short* kr = kbuf + (ct * 16 + c) * 64;
      short8 kf0 = *(const short8*)(kr + rseg0 * 8);
      short8 kf1 = *(const short8*)(kr + rseg1 * 8);
      f32x4 z0 = {-8.f, -8.f, -8.f, -8.f};
      z0 = __builtin_amdgcn_mfma_f32_16x16x32_bf16(kf0, qf0, z0, 0, 0, 0);
      z0 = __builtin_amdgcn_mfma_f32_16x16x32_bf16(kf1, qf1, z0, 0, 0, 0);
      s[ct] = z0;
    }
    // V fragments issued BEFORE the exp chain (latency hides under exp).
    short8 vf[4][2];
#pragma unroll
    for (int ct = 0; ct < 4; ct++) {
      const short* vr = vbuf + (ct * 16 + c) * 64;
      vf[ct][0] = *(const short8*)(vr + rseg0 * 8);
      vf[ct][1] = *(const short8*)(vr + rseg1 * 8);
    }
#pragma unroll
    for (int ct = 0; ct < 4; ct++)
#pragma unroll
      for (int r = 0; r < 4; r++) s[ct][r] = exp2f(s[ct][r]);
    // In-register P -> A-frag redistribution (T12-style, zero LDS).
    {
      int wA[4], wB[4];
#pragma unroll
      for (int ct = 0; ct < 4; ct++) {
        wA[ct] = (int)pkbf_trunc(s[ct][0], s[ct][1]);
        wB[ct] = (int)pkbf_trunc(s[ct][2], s[ct][3]);
      }
      // frag0 (kv 0..31 from ct0,ct1): words j0..j3 at quad q = kv q*8+2j.
      pl32swap(wA[0], wA[1]); pl16swap(wA[0], wA[1]);  // wA0=j0, wA1=j2
      pl32swap(wB[0], wB[1]); pl16swap(wB[0], wB[1]);  // wB0=j1, wB1=j3
      int4v f0 = {wA[0], wB[0], wA[1], wB[1]};
      // frag1 (kv 32..63 from ct2,ct3)
      pl32swap(wA[2], wA[3]); pl16swap(wA[2], wA[3]);
      pl32swap(wB[2], wB[3]); pl16swap(wB[2], wB[3]);
      int4v f1 = {wA[2], wB[2], wA[3], wB[3]};
      short8 pf0 = *(short8*)&f0;
      short8 pf1 = *(short8*)&f1;
#pragma unroll
      for (int ct = 0; ct < 4; ct++) {
        acc[ct] = __builtin_amdgcn_mfma_f32_16x16x32_bf16(pf0, vf[ct][0], acc[ct], 0, 0, 0);
        acc[ct] = __builtin_amdgcn_mfma_f32_16x16x32_bf16(pf1, vf[ct][1], acc[ct], 0, 0, 0);
      }
      acc[4] = __builtin_amdgcn_mfma_f32_16x16x32_bf16(pf0, onesf, acc[4], 0, 0, 0);
      acc[4] = __builtin_amdgcn_mfma_f32_16x16x32_bf16(pf1, onesf, acc[4], 0, 0, 0);
    }
  }
  int n = nh >> 2, h = nh & 3;
  {
    float linv[4];
#pragma unroll
    for (int r = 0; r < 4; r++)
      linv[r] = 1.0f / __shfl(acc[4][r], lane & 48);
    asm volatile("" ::: "memory");
#pragma unroll
    for (int t = 0; t < 4; t++) {
      int us_[4];
#pragma unroll
      for (int r = 0; r < 4; r++) us_[r] = f2bf_bits(acc[t][r] * linv[r]);
      int xv0 = dppx1i(us_[0]);
      int xv1 = dppx1i(us_[1]);
      int xv2 = dppx1i(us_[2]);
      int xv3 = dppx1i(us_[3]);
      if (ev) {
        *(int*)(pl + (quad * 4 + 0) * 66 + t * 16 + c) = (xv0 << 16) | us_[0];
        *(int*)(pl + (quad * 4 + 1) * 66 + t * 16 + c) = (xv1 << 16) | us_[1];
      } else {
        *(int*)(pl + (quad * 4 + 2) * 66 + t * 16 + (c - 1)) = (us_[2] << 16) | xv2;
        *(int*)(pl + (quad * 4 + 3) * 66 + t * 16 + (c - 1)) = (us_[3] << 16) | xv3;
      }
    }
    asm volatile("" ::: "memory");
    int row = lane >> 2, seg = lane & 3;
    short8 o0 = *(const short8*)(pl + row * 66 + seg * 16);
    short8 o1 = *(const short8*)(pl + row * 66 + seg * 16 + 8);
    short* dst = (short*)po +
                 ((size_t)n * 1600 + l0 + row) * 256 + h * 64 + seg * 16;
    *(short8*)(dst) = o0;
    *(short8*)(dst + 8) = o1;
    asm volatile("" ::: "memory");
  }
}

// ---------------------------------------------------------------------------
// K3: fused (1,9)conv+BN1+res+relu -> 1x1conv+BN2+res+relu -> d_out.
// A-tile staged in LDS (r16); W-frags register-double-buffered one
// (r,kc) step ahead, pinned by an asm clobber (wraparound indexing,
// undef-free). grid (25,16) x 256.
// ---------------------------------------------------------------------------
__global__ __launch_bounds__(256)
void k_conv9(const bf16* __restrict__ ot, const bf16* __restrict__ Wt,
             const float* __restrict__ bo, const float* __restrict__ g1,
             const float* __restrict__ be1, const float* __restrict__ mu1,
             const float* __restrict__ va1, const float* __restrict__ x,
             const bf16* __restrict__ WfT, const float* __restrict__ bff,
             const float* __restrict__ g2, const float* __restrict__ be2,
             const float* __restrict__ mu2, const float* __restrict__ va2,
             float* __restrict__ out) {
  __shared__ short abuf[72 * 256];  // ot rows l0b-4..l0b+67, swizzled segs
  __shared__ short tl[4][16 * 66];
  int tid = threadIdx.x;
  int wv = tid >> 6;
  int lane = tid & 63;
  int quad = lane >> 4, c = lane & 15;
  int n = blockIdx.y;
  int l0b = blockIdx.x * 64;
  int l0 = l0b + wv * 16;
  int la = l0 + c;
  int va = la % 25;
  const short* obase = (const short*)ot + (size_t)n * 409600;
  const short* wbase = (const short*)Wt;

  // --- stage A rows [l0b-4, l0b+68) into LDS (coalesced, swizzled) ---
#pragma unroll
  for (int it = 0; it < 9; it++) {
    int ch = tid + it * 256;
    int row = ch >> 5, seg = ch & 31;
    int gl = l0b - 4 + row;
    gl = max(0, min(1599, gl));  // clamp; clamped rows only feed masked lanes
    short8 v = *(const short8*)(obase + (size_t)gl * 256 + seg * 8);
    *(short8*)(abuf + row * 256 + (seg ^ (row & 7)) * 8) = v;
  }
  __syncthreads();

  f32x4 acc[4] = {};
  // W-frag register double-buffer: preload (r=0,kc=0).
  const short* wl = wbase + lane * 8;
  short8 bb0 = *(const short8*)(wl);
  short8 bb1 = *(const short8*)(wl + 512);
  short8 bb2 = *(const short8*)(wl + 1024);
  short8 bb3 = *(const short8*)(wl + 1536);
  for (int r = 0; r < 9; r++) {
    int sh = r - 4;
    bool valid = (unsigned)(va + sh) < 25u;
    int rl = wv * 16 + c + r;        // row in abuf (always in [0,71])
    int rx = rl & 7;
    const short* arow = abuf + rl * 256;
    short8 z8 = {0, 0, 0, 0, 0, 0, 0, 0};
#pragma unroll
    for (int kc = 0; kc < 8; kc++) {
      short8 b0 = bb0, b1 = bb1, b2 = bb2, b3 = bb3;
      // prefetch next (r,kc) step; wraparound on the final step keeps all
      // loads valid (zero undef -- r17 lesson).
      int nkc = (kc + 1) & 7;
      int nr = (kc == 7) ? ((r + 1 < 9) ? r + 1 : 0) : r;
      const short* wkn = wbase + (size_t)nr * 16384 + nkc * 2048 + lane * 8;
      bb0 = *(const short8*)(wkn);
      bb1 = *(const short8*)(wkn + 512);
      bb2 = *(const short8*)(wkn + 1024);
      bb3 = *(const short8*)(wkn + 1536);
      asm volatile("" ::: "memory");  // pin prefetch issue point
      int seg = (quad + kc * 4) ^ rx;
      short8 af = *(const short8*)(arow + seg * 8);
      af = valid ? af : z8;
      acc[0] = __builtin_amdgcn_mfma_f32_16x16x32_bf16(af, b0, acc[0], 0, 0, 0);
      acc[1] = __builtin_amdgcn_mfma_f32_16x16x32_bf16(af, b1, acc[1], 0, 0, 0);
      acc[2] = __builtin_amdgcn_mfma_f32_16x16x32_bf16(af, b2, acc[2], 0, 0, 0);
      acc[3] = __builtin_amdgcn_mfma_f32_16x16x32_bf16(af, b3, acc[3], 0, 0, 0);
    }
  }
  // --- epilogue 1: BN1 + bias + residual x + relu -> outv (regs only) ---
  short* tlw = &tl[wv][0];
  float outv[4][4];
#pragma unroll
  for (int cot = 0; cot < 4; cot++) {
    int co = cot * 16 + c;
    float inv = g1[co] * rsqrtf(va1[co] + 1e-5f);
    float add = be1[co] - mu1[co] * inv + bo[co] * inv;
    f32x4 xr = *(const f32x4*)(x + (size_t)(n * 64 + co) * 1600 + l0 + quad * 4);
#pragma unroll
    for (int rr = 0; rr < 4; rr++)
      outv[cot][rr] = fmaxf(acc[cot][rr] * inv + add + xr[rr], 0.f);
  }
  // --- y^T tile via wave-private LDS [16 l][66 ci] (DPP pairing) ---
  asm volatile("" ::: "memory");
  bool ev = (c & 1) == 0;
#pragma unroll
  for (int cot = 0; cot < 4; cot++) {
    int us_[4];
#pragma unroll
    for (int rr = 0; rr < 4; rr++) us_[rr] = f2bf_bits(outv[cot][rr]);
    int xv0 = dppx1i(us_[0]);
    int xv1 = dppx1i(us_[1]);
    int xv2 = dppx1i(us_[2]);
    int xv3 = dppx1i(us_[3]);
    if (ev) {
      *(int*)(tlw + (quad * 4 + 0) * 66 + cot * 16 + c) = (xv0 << 16) | us_[0];
      *(int*)(tlw + (quad * 4 + 1) * 66 + cot * 16 + c) = (xv1 << 16) | us_[1];
    } else {
      *(int*)(tlw + (quad * 4 + 2) * 66 + cot * 16 + (c - 1)) = (us_[2] << 16) | xv2;
      *(int*)(tlw + (quad * 4 + 3) * 66 + cot * 16 + (c - 1)) = (us_[3] << 16) | xv3;
    }
  }
  asm volatile("" ::: "memory");
  // --- fused ff: A-frags straight from tl (A[m=l][k=ci]) ---
  short8 afY0 = *(const short8*)(tlw + c * 66 + quad * 8);
  short8 afY1 = *(const short8*)(tlw + c * 66 + 32 + quad * 8);
  const short* wfb = (const short*)WfT + lane * 8;
  f32x4 acc2[4] = {};
#pragma unroll
  for (int kc = 0; kc < 2; kc++) {
    short8 afk = kc ? afY1 : afY0;
    const short* wk = wfb + kc * 2048;
    short8 b0 = *(const short8*)(wk);
    short8 b1 = *(const short8*)(wk + 512);
    short8 b2 = *(const short8*)(wk + 1024);
    short8 b3 = *(const short8*)(wk + 1536);
    acc2[0] = __builtin_amdgcn_mfma_f32_16x16x32_bf16(afk, b0, acc2[0], 0, 0, 0);
    acc2[1] = __builtin_amdgcn_mfma_f32_16x16x32_bf16(afk, b1, acc2[1], 0, 0, 0);
    acc2[2] = __builtin_amdgcn_mfma_f32_16x16x32_bf16(afk, b2, acc2[2], 0, 0, 0);
    acc2[3] = __builtin_amdgcn_mfma_f32_16x16x32_bf16(afk, b3, acc2[3], 0, 0, 0);
  }
  // --- epilogue 2: BN2 + bias + residual y(=outv) + relu -> d_out fp32 ---
#pragma unroll
  for (int cot = 0; cot < 4; cot++) {
    int co = cot * 16 + c;
    float inv = g2[co] * rsqrtf(va2[co] + 1e-5f);
    float add = be2[co] - mu2[co] * inv + bff[co] * inv;
    f32x4 ov;
#pragma unroll
    for (int rr = 0; rr < 4; rr++)
      ov[rr] = fmaxf(acc2[cot][rr] * inv + add + outv[cot][rr], 0.f);
    *(f32x4*)(out + (size_t)(n * 64 + co) * 1600 + l0 + quad * 4) = ov;
  }
}

extern "C" void kernel_launch(void* const* d_in, const int* in_sizes, int n_in,
                              void* d_out, int out_size, void* d_ws, size_t ws_size,
                              hipStream_t stream) {
  const float* x   = (const float*)d_in[0];
  const float* Wq  = (const float*)d_in[1];
  const float* bq  = (const float*)d_in[2];
  const float* Wo  = (const float*)d_in[3];
  const float* bo  = (const float*)d_in[4];
  const float* g1  = (const float*)d_in[5];
  const float* be1 = (const float*)d_in[6];
  const float* mu1 = (const float*)d_in[7];
  const float* va1 = (const float*)d_in[8];
  const float* Wf  = (const float*)d_in[9];
  const float* bff = (const float*)d_in[10];
  const float* g2  = (const float*)d_in[11];
  const float* be2 = (const float*)d_in[12];
  const float* mu2 = (const float*)d_in[13];
  const float* va2 = (const float*)d_in[14];

  const size_t QKV = (size_t)64 * 1600 * 64;  // 6,553,600 bf16 elems
  // split=1 layout: q,k,vt,po (4*QKV) + weights. ~52.8 MB.
  bf16* qw  = (bf16*)d_ws;
  bf16* kw  = qw + QKV;
  bf16* vtw = kw + QKV;
  bf16* pow_ = vtw + QKV;                      // po == ot for conv9
  bf16* Wt  = pow_ + QKV;
  bf16* WfT = Wt + 147456;
  bf16* WqT = WfT + 4096;

  k_prep_wq<<<192, 256, 0, stream>>>(Wq, WqT);
  k_qkv<<<400, 256, 0, stream>>>(x, WqT, bq, qw, kw, vtw);
  k_attn<<<1600 + 576, 256, 0, stream>>>(qw, kw, vtw, pow_, Wo, Wf, Wt, WfT);
  dim3 gc(25, 16);
  k_conv9<<<gc, 256, 0, stream>>>(pow_, Wt, bo, g1, be1, mu1, va1, x,
                                  WfT, bff, g2, be2, mu2, va2, (float*)d_out);
}